// Round 3
// baseline (348.320 us; speedup 1.0000x reference)
//
#include <hip/hip_runtime.h>
#include <hip/hip_bf16.h>

// Per-row mode, N=1048576 rows x K=64 cols, values are floats in {0..7}.
//
// R2 lesson: 16-lanes/row was coalesced but paid 8 ds_swizzle per thread
// (64-bit shfl x4 steps) across 16M tiny threads (~22us of DS-pipe per CU).
// R3: 4 lanes/row, 16 elems/lane. Each wave-load still reads fully-consumed
// 64B granules (16 rows x 64B segments); reduction is 2 shfl_xor steps
// (masks 1,2 stay inside the 4-lane group); 4 independent float4 loads per
// thread for memory-level parallelism.
//
// Histogram: 8 bins packed 8-bits-each in one uint64 (max count 64 < 256).
// Tie-break: strict > scan from v=0 -> smallest value wins, matching
// torch.mode / the reference argmax-on-sorted.

#define K 64

__global__ __launch_bounds__(256) void mode_rows_kernel(
    const float* __restrict__ x, float* __restrict__ out, int nrows) {
    int tid = blockIdx.x * blockDim.x + threadIdx.x;
    int row = tid >> 2;        // 4 lanes per row
    int sub = tid & 3;
    if (row >= nrows) return;

    const float4* p = (const float4*)(x + (size_t)row * K);

    // issue all 4 loads up front (independent -> overlapped misses)
    float4 v0 = p[sub];
    float4 v1 = p[4 + sub];
    float4 v2 = p[8 + sub];
    float4 v3 = p[12 + sub];

    unsigned long long cnt = 0ULL;
    cnt += 1ULL << (((int)v0.x) << 3);
    cnt += 1ULL << (((int)v0.y) << 3);
    cnt += 1ULL << (((int)v0.z) << 3);
    cnt += 1ULL << (((int)v0.w) << 3);
    cnt += 1ULL << (((int)v1.x) << 3);
    cnt += 1ULL << (((int)v1.y) << 3);
    cnt += 1ULL << (((int)v1.z) << 3);
    cnt += 1ULL << (((int)v1.w) << 3);
    cnt += 1ULL << (((int)v2.x) << 3);
    cnt += 1ULL << (((int)v2.y) << 3);
    cnt += 1ULL << (((int)v2.z) << 3);
    cnt += 1ULL << (((int)v2.w) << 3);
    cnt += 1ULL << (((int)v3.x) << 3);
    cnt += 1ULL << (((int)v3.y) << 3);
    cnt += 1ULL << (((int)v3.z) << 3);
    cnt += 1ULL << (((int)v3.w) << 3);

    // sum 4 partial histograms (stays within the 4-lane group)
    cnt += (unsigned long long)__shfl_xor((unsigned long long)cnt, 1);
    cnt += (unsigned long long)__shfl_xor((unsigned long long)cnt, 2);

    if (sub == 0) {
        int best_v = 0;
        int best_c = -1;
        #pragma unroll
        for (int b = 0; b < 8; ++b) {
            int c = (int)((cnt >> (b << 3)) & 0xFFULL);
            if (c > best_c) { best_c = c; best_v = b; }
        }
        out[row] = (float)best_v;   // 16 consecutive floats per wave: 64B store
    }
}

extern "C" void kernel_launch(void* const* d_in, const int* in_sizes, int n_in,
                              void* d_out, int out_size, void* d_ws, size_t ws_size,
                              hipStream_t stream) {
    const float* x = (const float*)d_in[0];
    float* out = (float*)d_out;
    int nrows = in_sizes[0] / K;

    const int block = 256;                       // 64 rows per block
    const int grid = (nrows * 4 + block - 1) / block;
    mode_rows_kernel<<<grid, block, 0, stream>>>(x, out, nrows);
}

// Round 4
// 337.073 us; speedup vs baseline: 1.0334x; 1.0334x over previous
//
#include <hip/hip_runtime.h>
#include <hip/hip_bf16.h>

// Per-row mode, N=1048576 rows x K=64 cols, values are floats in {0..7}.
//
// Final structure (= R2, the best-measured variant): 16 lanes per row, each
// lane loads one float4 -> each wave-load instruction reads 4 fully-
// contiguous 256B row segments (1 KiB/instr, perfectly coalesced). Per-lane
// packed histogram: 8 bins x 8 bits in one uint64 (row count 64 < 256, no
// overflow). 4-step shfl_xor (masks 1,2,4,8 stay inside the 16-lane group)
// sums the partials; lane 0 scans bins with strict > from v=0 so ties give
// the smallest value (torch.mode semantics).
//
// R1 showed 1-thread/row (256B lane stride) costs ~+16us; R3 showed cutting
// DS work 8x is neutral-to-worse -- kernel is at the HBM read floor
// (256MB in + 4MB out ~= 40us at the ~6.7 TB/s this device sustains);
// dur_us residual is fixed harness restore/poison traffic.

#define K 64

__global__ __launch_bounds__(256) void mode_rows_kernel(
    const float* __restrict__ x, float* __restrict__ out, int nrows) {
    int tid = blockIdx.x * blockDim.x + threadIdx.x;
    int row = tid >> 4;        // 16 lanes per row
    int sub = tid & 15;
    if (row >= nrows) return;

    float4 v = ((const float4*)(x + (size_t)row * K))[sub];

    unsigned long long cnt = 0ULL;
    cnt += 1ULL << (((int)v.x) << 3);
    cnt += 1ULL << (((int)v.y) << 3);
    cnt += 1ULL << (((int)v.z) << 3);
    cnt += 1ULL << (((int)v.w) << 3);

    #pragma unroll
    for (int m = 1; m < 16; m <<= 1)
        cnt += (unsigned long long)__shfl_xor((unsigned long long)cnt, m);

    if (sub == 0) {
        int best_v = 0;
        int best_c = -1;
        #pragma unroll
        for (int b = 0; b < 8; ++b) {
            int c = (int)((cnt >> (b << 3)) & 0xFFULL);
            if (c > best_c) { best_c = c; best_v = b; }
        }
        out[row] = (float)best_v;
    }
}

extern "C" void kernel_launch(void* const* d_in, const int* in_sizes, int n_in,
                              void* d_out, int out_size, void* d_ws, size_t ws_size,
                              hipStream_t stream) {
    const float* x = (const float*)d_in[0];
    float* out = (float*)d_out;
    int nrows = in_sizes[0] / K;

    const int block = 256;                       // 16 rows per block
    const int grid = (nrows * 16 + block - 1) / block;
    mode_rows_kernel<<<grid, block, 0, stream>>>(x, out, nrows);
}